// Round 7
// baseline (238.323 us; speedup 1.0000x reference)
//
#include <hip/hip_runtime.h>
#include <math.h>

#define LLEN 256
#define HDIM 256
#define MM 1024
#define NEGV -4294967295.0f

// ---- GEMM core: C = [rmsnorm?](A) @ W^T + bias (+epilogue) ----------------
// BM=64, BN=64, BK=64, 256 thr, per-thread 4m x 4n. Rows 4tm+i (A reads are
// 4-address wave-broadcasts, 2-way banks); cols tn+16j (W reads at pad-68 ->
// banks tn*4%32, 2 addrs/bank ~ free). 8 b128 (96cy) per 128 fma-cy per k4.
__device__ __forceinline__ void gemm_core(
    float* A_s, float* W_s, float* r_s,
    const float* __restrict__ A, const float* __restrict__ ln,
    const float* __restrict__ W, const float* __restrict__ bias,
    const float* __restrict__ addv, const float* __restrict__ resid,
    const unsigned char* __restrict__ tl, float* __restrict__ C,
    int relu, int m0, int n0)
{
    int t = threadIdx.x;
    int srow = t >> 4, sc4 = t & 15;      // staging: rows srow+16i, float4-col sc4
    int tm = t >> 4, tn = t & 15;         // compute: rows 4tm+i, cols tn+16j
    float acc[4][4];
    #pragma unroll
    for (int i = 0; i < 4; ++i)
        #pragma unroll
        for (int j = 0; j < 4; ++j) acc[i][j] = 0.f;
    float ssq[4] = {0.f, 0.f, 0.f, 0.f};

    for (int kc = 0; kc < HDIM; kc += 64) {
        #pragma unroll
        for (int i = 0; i < 4; ++i) {                 // stage A+W: 64 rows x 64 k
            int row = srow + 16 * i;
            float4 va = *(const float4*)&A[(size_t)(m0 + row) * HDIM + kc + sc4 * 4];
            ssq[i] += va.x*va.x + va.y*va.y + va.z*va.z + va.w*va.w;
            if (ln) {
                va.x *= ln[kc + sc4*4 + 0]; va.y *= ln[kc + sc4*4 + 1];
                va.z *= ln[kc + sc4*4 + 2]; va.w *= ln[kc + sc4*4 + 3];
            }
            *(float4*)&A_s[row * 68 + sc4 * 4] = va;
            *(float4*)&W_s[row * 68 + sc4 * 4] =
                *(const float4*)&W[(size_t)(n0 + row) * HDIM + kc + sc4 * 4];
        }
        __syncthreads();
        #pragma unroll 4
        for (int k4 = 0; k4 < 16; ++k4) {
            float4 a[4], wv[4];
            #pragma unroll
            for (int i = 0; i < 4; ++i)
                a[i] = *(const float4*)&A_s[(4*tm + i) * 68 + k4 * 4];  // broadcast
            #pragma unroll
            for (int j = 0; j < 4; ++j)
                wv[j] = *(const float4*)&W_s[(tn + 16*j) * 68 + k4 * 4];
            #pragma unroll
            for (int i = 0; i < 4; ++i)
                #pragma unroll
                for (int j = 0; j < 4; ++j)
                    acc[i][j] = fmaf(a[i].x, wv[j].x, fmaf(a[i].y, wv[j].y,
                                fmaf(a[i].z, wv[j].z, fmaf(a[i].w, wv[j].w, acc[i][j]))));
        }
        __syncthreads();
    }

    if (ln) {   // row rsqrt factors; thread's ssq covers staging rows srow+16i
        #pragma unroll
        for (int i = 0; i < 4; ++i) {
            float v = ssq[i];
            v += __shfl_xor(v, 1); v += __shfl_xor(v, 2);
            v += __shfl_xor(v, 4); v += __shfl_xor(v, 8);
            if (sc4 == 0) r_s[srow + 16 * i] = rsqrtf(v * (1.0f / HDIM) + 1e-8f);
        }
        __syncthreads();
    }

    #pragma unroll
    for (int i = 0; i < 4; ++i) {
        int row = m0 + 4*tm + i;
        float rr = ln ? r_s[4*tm + i] : 1.0f;
        float tlf = tl ? (tl[row] ? 0.f : 1.f) : 1.f;
        #pragma unroll
        for (int j = 0; j < 4; ++j) {
            int col = n0 + tn + 16*j;
            float v = acc[i][j] * rr + bias[col];
            if (relu) v = fmaxf(v, 0.f);
            size_t idx = (size_t)row * HDIM + col;
            if (addv)  v += addv[idx];
            if (resid) v += resid[idx];
            v *= tlf;
            C[idx] = v;
        }
    }
}

__global__ __launch_bounds__(256) void qkv_kernel(
    const float* __restrict__ s, const float* __restrict__ ln_attn,
    const float* __restrict__ Qw, const float* __restrict__ Qb,
    const float* __restrict__ Kw, const float* __restrict__ Kb,
    const float* __restrict__ Vw, const float* __restrict__ Vb,
    const float* __restrict__ apK, const float* __restrict__ apV,
    float* __restrict__ qb, float* __restrict__ kb, float* __restrict__ vb)
{
    __shared__ __align__(16) float A_s[64 * 68];
    __shared__ __align__(16) float W_s[64 * 68];
    __shared__ float r_s[64];
    int m0 = blockIdx.x * 64;
    int sel = blockIdx.y >> 2;
    int n0 = (blockIdx.y & 3) * 64;
    if (sel == 0)
        gemm_core(A_s, W_s, r_s, s, ln_attn, Qw, Qb, nullptr, nullptr, nullptr, qb, 0, m0, n0);
    else if (sel == 1)
        gemm_core(A_s, W_s, r_s, s, nullptr, Kw, Kb, apK, nullptr, nullptr, kb, 0, m0, n0);
    else
        gemm_core(A_s, W_s, r_s, s, nullptr, Vw, Vb, apV, nullptr, nullptr, vb, 0, m0, n0);
}

__global__ __launch_bounds__(256) void gemm_kernel(
    const float* __restrict__ A, const float* __restrict__ ln,
    const float* __restrict__ W, const float* __restrict__ bias,
    const float* __restrict__ resid, const unsigned char* __restrict__ tl,
    float* __restrict__ C, int relu)
{
    __shared__ __align__(16) float A_s[64 * 68];
    __shared__ __align__(16) float W_s[64 * 68];
    __shared__ float r_s[64];
    gemm_core(A_s, W_s, r_s, A, ln, W, bias, nullptr, resid, tl, C, relu,
              blockIdx.x * 64, blockIdx.y * 64);
}

// ---- Attention: one WG (1024 thr, 16 waves) per complementary row pair ----
// 512 WGs x 16 waves = 32 waves/CU exact fill, uniform work (257 k-rows).
// Both rows' phases merged: score(q0)+score(q1) | softmax x8waves | PV(q0)+
// PV(q1) | reduce q0 | reduce q1. 2-deep load prefetch in all k-loops.
__global__ __launch_bounds__(1024, 8) void attn_kernel(
    const float* __restrict__ Q, const float* __restrict__ Kp,
    const float* __restrict__ Vp, const float* __restrict__ tmK,
    const float* __restrict__ tmV, const unsigned char* __restrict__ tl,
    const float* __restrict__ src, float* __restrict__ dst)
{
    int g = blockIdx.x;
    int b = g >> 7, p = g & 127;
    int tid = threadIdx.x;
    int w = tid >> 6, lane = tid & 63;
    int hh = lane >> 4;

    __shared__ float w_s[2][4][257];
    __shared__ __align__(16) float out_s[16][256];

    int q0 = p, q1 = 255 - p;
    int bq0 = b * 256 + q0, bq1 = b * 256 + q1;
    float4 qf0 = ((const float4*)(Q + (size_t)bq0 * HDIM))[lane];
    float4 qf1 = ((const float4*)(Q + (size_t)bq1 * HDIM))[lane];
    bool tl0 = tl[bq0] != 0, tl1 = tl[bq1] != 0;
    int kmax0 = tl0 ? (LLEN - 1) : q0;   // causal skip: masked cols -> A==0 exactly
    int kmax1 = tl1 ? (LLEN - 1) : q1;

    const float4* Kp4 = (const float4*)(Kp + (size_t)b * LLEN * HDIM);
    const float4* Vp4 = (const float4*)(Vp + (size_t)b * LLEN * HDIM);
    const float4* tmK0 = (const float4*)(tmK + (size_t)bq0 * LLEN * HDIM);
    const float4* tmK1 = (const float4*)(tmK + (size_t)bq1 * LLEN * HDIM);
    const float4* tmV0 = (const float4*)(tmV + (size_t)bq0 * LLEN * HDIM);
    const float4* tmV1 = (const float4*)(tmV + (size_t)bq1 * LLEN * HDIM);

    // ---- phase 1: scores for both rows (prefetched) ----
    #pragma unroll
    for (int rr = 0; rr < 2; ++rr) {
        int kmax = rr ? kmax1 : kmax0;
        const float4* tmK4 = rr ? tmK1 : tmK0;
        float4 qf = rr ? qf1 : qf0;
        int k = w;
        if (k <= kmax) {
            float4 kv = Kp4[k * 64 + lane];
            float4 tv = tmK4[k * 64 + lane];
            while (true) {
                int kn = k + 16;
                bool more = (kn <= kmax);
                float4 kv2, tv2;
                if (more) { kv2 = Kp4[kn * 64 + lane]; tv2 = tmK4[kn * 64 + lane]; }
                float sc = qf.x * (kv.x + tv.x) + qf.y * (kv.y + tv.y)
                         + qf.z * (kv.z + tv.z) + qf.w * (kv.w + tv.w);
                sc += __shfl_xor(sc, 1);
                sc += __shfl_xor(sc, 2);
                sc += __shfl_xor(sc, 4);
                sc += __shfl_xor(sc, 8);
                if ((lane & 15) == 0) w_s[rr][lane >> 4][k] = sc;
                if (!more) break;
                kv = kv2; tv = tv2; k = kn;
            }
        }
    }
    __syncthreads();

    // ---- softmax: 8 waves (r = row, h = head); mask folded, stale unused ----
    if (w < 8) {
        int r = w >> 2, h = w & 3;
        int q = r ? q1 : q0;
        bool tlq = r ? tl1 : tl0;
        float v0 = w_s[r][h][lane],       v1 = w_s[r][h][lane + 64];
        float v2 = w_s[r][h][lane + 128], v3 = w_s[r][h][lane + 192];
        v0 = (tlq || (lane       > q)) ? NEGV : v0 * 0.125f;
        v1 = (tlq || (lane + 64  > q)) ? NEGV : v1 * 0.125f;
        v2 = (tlq || (lane + 128 > q)) ? NEGV : v2 * 0.125f;
        v3 = (tlq || (lane + 192 > q)) ? NEGV : v3 * 0.125f;
        float mx = fmaxf(fmaxf(v0, v1), fmaxf(v2, v3));
        #pragma unroll
        for (int m2 = 1; m2 < 64; m2 <<= 1) mx = fmaxf(mx, __shfl_xor(mx, m2));
        float e0 = __expf(v0 - mx), e1 = __expf(v1 - mx);
        float e2 = __expf(v2 - mx), e3 = __expf(v3 - mx);
        float sm = e0 + e1 + e2 + e3;
        #pragma unroll
        for (int m2 = 1; m2 < 64; m2 <<= 1) sm += __shfl_xor(sm, m2);
        float inv = 1.0f / sm;
        w_s[r][h][lane] = e0 * inv;       w_s[r][h][lane + 64] = e1 * inv;
        w_s[r][h][lane + 128] = e2 * inv; w_s[r][h][lane + 192] = e3 * inv;
    }
    __syncthreads();

    // ---- phase 2: PV for both rows (prefetched) ----
    float4 acc0 = {0.f, 0.f, 0.f, 0.f}, acc1 = {0.f, 0.f, 0.f, 0.f};
    #pragma unroll
    for (int rr = 0; rr < 2; ++rr) {
        int kmax = rr ? kmax1 : kmax0;
        const float4* tmV4 = rr ? tmV1 : tmV0;
        float4 acc = {0.f, 0.f, 0.f, 0.f};
        int k = w;
        if (k <= kmax) {
            float4 vv = Vp4[k * 64 + lane];
            float4 tv = tmV4[k * 64 + lane];
            while (true) {
                int kn = k + 16;
                bool more = (kn <= kmax);
                float4 vv2, tv2;
                if (more) { vv2 = Vp4[kn * 64 + lane]; tv2 = tmV4[kn * 64 + lane]; }
                float a = w_s[rr][hh][k];
                acc.x = fmaf(a, vv.x + tv.x, acc.x);
                acc.y = fmaf(a, vv.y + tv.y, acc.y);
                acc.z = fmaf(a, vv.z + tv.z, acc.z);
                acc.w = fmaf(a, vv.w + tv.w, acc.w);
                if (!more) break;
                vv = vv2; tv = tv2; k = kn;
            }
        }
        if (rr) acc1 = acc; else acc0 = acc;
    }

    // ---- reduce + residual-add, row q0 then q1 (out_s reused) ----
    *(float4*)&out_s[w][lane * 4] = acc0;
    __syncthreads();
    if (tid < 256) {
        float pp = 0.f;
        #pragma unroll
        for (int j = 0; j < 16; ++j) pp += out_s[j][tid];
        size_t idx = (size_t)bq0 * HDIM + tid;
        dst[idx] = src[idx] + pp;
    }
    __syncthreads();
    *(float4*)&out_s[w][lane * 4] = acc1;
    __syncthreads();
    if (tid < 256) {
        float pp = 0.f;
        #pragma unroll
        for (int j = 0; j < 16; ++j) pp += out_s[j][tid];
        size_t idx = (size_t)bq1 * HDIM + tid;
        dst[idx] = src[idx] + pp;
    }
}

// ---- final RMSNorm --------------------------------------------------------
__global__ __launch_bounds__(256) void rmsnorm_kernel(
    const float* __restrict__ x, const float* __restrict__ w, float* __restrict__ y)
{
    int row = blockIdx.x;
    int tid = threadIdx.x;
    float v = x[(size_t)row * HDIM + tid];
    float ss = v * v;
    #pragma unroll
    for (int m = 1; m < 64; m <<= 1) ss += __shfl_xor(ss, m);
    __shared__ float red[4];
    if ((tid & 63) == 0) red[tid >> 6] = ss;
    __syncthreads();
    float tot = red[0] + red[1] + red[2] + red[3];
    float r = rsqrtf(tot * (1.0f / HDIM) + 1e-8f);
    y[(size_t)row * HDIM + tid] = v * r * w[tid];
}

extern "C" void kernel_launch(void* const* d_in, const int* in_sizes, int n_in,
                              void* d_out, int out_size, void* d_ws, size_t ws_size,
                              hipStream_t stream)
{
    const float* seqs = (const float*)d_in[0];
    const unsigned char* tl = (const unsigned char*)d_in[2];
    const float* tmK = (const float*)d_in[3];
    const float* tmV = (const float*)d_in[4];
    const float* apK = (const float*)d_in[5];
    const float* apV = (const float*)d_in[6];
    const float* ln_attn = (const float*)d_in[7];
    const float* Qw = (const float*)d_in[8];
    const float* Qb = (const float*)d_in[9];
    const float* Kw = (const float*)d_in[10];
    const float* Kb = (const float*)d_in[11];
    const float* Vw = (const float*)d_in[12];
    const float* Vb = (const float*)d_in[13];
    const float* ln_ffn = (const float*)d_in[14];
    const float* W1 = (const float*)d_in[15];
    const float* b1 = (const float*)d_in[16];
    const float* W2 = (const float*)d_in[17];
    const float* b2 = (const float*)d_in[18];
    const float* ln_last = (const float*)d_in[19];
    float* out = (float*)d_out;

    const size_t NROW = (size_t)MM * HDIM;
    float* s  = (float*)d_ws;
    float* qb = s  + NROW;
    float* kb = qb + NROW;
    float* vb = kb + NROW;
    float* tb = vb + NROW;

    for (int i = 0; i < 2; ++i) {
        const float* Qwi = Qw + (size_t)i * HDIM * HDIM;
        const float* Kwi = Kw + (size_t)i * HDIM * HDIM;
        const float* Vwi = Vw + (size_t)i * HDIM * HDIM;
        const float* W1i = W1 + (size_t)i * HDIM * HDIM;
        const float* W2i = W2 + (size_t)i * HDIM * HDIM;
        const float* cur = (i == 0) ? seqs : s;   // block0 reads seqs directly

        qkv_kernel<<<dim3(16, 12), 256, 0, stream>>>(
            cur, ln_attn + i * HDIM, Qwi, Qb + i * HDIM, Kwi, Kb + i * HDIM,
            Vwi, Vb + i * HDIM, apK, apV, qb, kb, vb);
        attn_kernel<<<512, 1024, 0, stream>>>(qb, kb, vb, tmK, tmV, tl, cur, s);
        gemm_kernel<<<dim3(16, 4), 256, 0, stream>>>(
            s, ln_ffn + i * HDIM, W1i, b1 + i * HDIM, nullptr, nullptr, tb, 1);
        gemm_kernel<<<dim3(16, 4), 256, 0, stream>>>(
            tb, nullptr, W2i, b2 + i * HDIM, s, tl, s, 0);
    }
    rmsnorm_kernel<<<MM, 256, 0, stream>>>(s, ln_last, out);
}

// Round 8
// 199.819 us; speedup vs baseline: 1.1927x; 1.1927x over previous
//
#include <hip/hip_runtime.h>
#include <math.h>

#define LLEN 256
#define HDIM 256
#define MM 1024
#define NEGV -4294967295.0f

// ---- GEMM core: C = [rmsnorm?](A) @ W^T + bias (+epilogue) ----------------
// BM=32, BN=64, BK=64, 256 thr (r6-proven). Per-thread 2m x 4n; cols tn+16j
// (W reads 2-way banks ~ free); A reads wave-uniform broadcasts.
__device__ __forceinline__ void gemm_core(
    float* A_s, float* W_s, float* r_s,
    const float* __restrict__ A, const float* __restrict__ ln,
    const float* __restrict__ W, const float* __restrict__ bias,
    const float* __restrict__ addv, const float* __restrict__ resid,
    const unsigned char* __restrict__ tl, float* __restrict__ C,
    int relu, int m0, int n0)
{
    int t = threadIdx.x;
    int srow = t >> 4, sc4 = t & 15;      // staging: A rows srow,srow+16; W rows srow+16i
    int tm = t >> 4, tn = t & 15;         // compute: rows 2tm..+1, cols tn+16j
    float acc[2][4];
    #pragma unroll
    for (int i = 0; i < 2; ++i)
        #pragma unroll
        for (int j = 0; j < 4; ++j) acc[i][j] = 0.f;
    float ssq[2] = {0.f, 0.f};

    for (int kc = 0; kc < HDIM; kc += 64) {
        #pragma unroll
        for (int i = 0; i < 2; ++i) {                 // stage A: 32 rows x 64 k
            int row = srow + 16 * i;
            float4 va = *(const float4*)&A[(size_t)(m0 + row) * HDIM + kc + sc4 * 4];
            ssq[i] += va.x*va.x + va.y*va.y + va.z*va.z + va.w*va.w;
            if (ln) {
                va.x *= ln[kc + sc4*4 + 0]; va.y *= ln[kc + sc4*4 + 1];
                va.z *= ln[kc + sc4*4 + 2]; va.w *= ln[kc + sc4*4 + 3];
            }
            *(float4*)&A_s[row * 68 + sc4 * 4] = va;
        }
        #pragma unroll
        for (int i = 0; i < 4; ++i) {                 // stage W: 64 rows x 64 k
            int row = srow + 16 * i;
            *(float4*)&W_s[row * 68 + sc4 * 4] =
                *(const float4*)&W[(size_t)(n0 + row) * HDIM + kc + sc4 * 4];
        }
        __syncthreads();
        #pragma unroll 4
        for (int k4 = 0; k4 < 16; ++k4) {
            float4 a0 = *(const float4*)&A_s[(2*tm + 0) * 68 + k4 * 4]; // broadcast
            float4 a1 = *(const float4*)&A_s[(2*tm + 1) * 68 + k4 * 4];
            #pragma unroll
            for (int j = 0; j < 4; ++j) {
                float4 wv = *(const float4*)&W_s[(tn + 16*j) * 68 + k4 * 4];
                acc[0][j] = fmaf(a0.x, wv.x, fmaf(a0.y, wv.y,
                            fmaf(a0.z, wv.z, fmaf(a0.w, wv.w, acc[0][j]))));
                acc[1][j] = fmaf(a1.x, wv.x, fmaf(a1.y, wv.y,
                            fmaf(a1.z, wv.z, fmaf(a1.w, wv.w, acc[1][j]))));
            }
        }
        __syncthreads();
    }

    if (ln) {
        #pragma unroll
        for (int i = 0; i < 2; ++i) {
            float v = ssq[i];
            v += __shfl_xor(v, 1); v += __shfl_xor(v, 2);
            v += __shfl_xor(v, 4); v += __shfl_xor(v, 8);
            if (sc4 == 0) r_s[srow + 16 * i] = rsqrtf(v * (1.0f / HDIM) + 1e-8f);
        }
        __syncthreads();
    }

    #pragma unroll
    for (int i = 0; i < 2; ++i) {
        int row = m0 + 2*tm + i;
        float rr = ln ? r_s[2*tm + i] : 1.0f;
        float tlf = tl ? (tl[row] ? 0.f : 1.f) : 1.f;
        #pragma unroll
        for (int j = 0; j < 4; ++j) {
            int col = n0 + tn + 16*j;
            float v = acc[i][j] * rr + bias[col];
            if (relu) v = fmaxf(v, 0.f);
            size_t idx = (size_t)row * HDIM + col;
            if (addv)  v += addv[idx];
            if (resid) v += resid[idx];
            v *= tlf;
            C[idx] = v;
        }
    }
}

__global__ __launch_bounds__(256) void qkv_kernel(
    const float* __restrict__ s, const float* __restrict__ ln_attn,
    const float* __restrict__ Qw, const float* __restrict__ Qb,
    const float* __restrict__ Kw, const float* __restrict__ Kb,
    const float* __restrict__ Vw, const float* __restrict__ Vb,
    const float* __restrict__ apK, const float* __restrict__ apV,
    float* __restrict__ qb, float* __restrict__ kb, float* __restrict__ vb)
{
    __shared__ __align__(16) float A_s[32 * 68];
    __shared__ __align__(16) float W_s[64 * 68];
    __shared__ float r_s[32];
    int m0 = blockIdx.x * 32;
    int sel = blockIdx.y >> 2;
    int n0 = (blockIdx.y & 3) * 64;
    if (sel == 0)
        gemm_core(A_s, W_s, r_s, s, ln_attn, Qw, Qb, nullptr, nullptr, nullptr, qb, 0, m0, n0);
    else if (sel == 1)
        gemm_core(A_s, W_s, r_s, s, nullptr, Kw, Kb, apK, nullptr, nullptr, kb, 0, m0, n0);
    else
        gemm_core(A_s, W_s, r_s, s, nullptr, Vw, Vb, apV, nullptr, nullptr, vb, 0, m0, n0);
}

__global__ __launch_bounds__(256) void gemm_kernel(
    const float* __restrict__ A, const float* __restrict__ ln,
    const float* __restrict__ W, const float* __restrict__ bias,
    const float* __restrict__ resid, const unsigned char* __restrict__ tl,
    float* __restrict__ C, int relu)
{
    __shared__ __align__(16) float A_s[32 * 68];
    __shared__ __align__(16) float W_s[64 * 68];
    __shared__ float r_s[32];
    gemm_core(A_s, W_s, r_s, A, ln, W, bias, nullptr, resid, tl, C, relu,
              blockIdx.x * 32, blockIdx.y * 64);
}

// ---- Attention: single-pass online softmax, one WG per row pair -----------
// 512 WGs x 16 waves = 32 waves/CU exact fill, uniform work (257 k-rows).
// Per k-row (one iter): load Kp,tmK,Vp,tmV rows (4x1KB, shared offset),
// 16-lane score reduce, online (m,l,acc) update in-register. No score LDS,
// no softmax phase. Final 16-wave flash-combine per row.
__global__ __launch_bounds__(1024, 8) void attn_kernel(
    const float* __restrict__ Q, const float* __restrict__ Kp,
    const float* __restrict__ Vp, const float* __restrict__ tmK,
    const float* __restrict__ tmV, const unsigned char* __restrict__ tl,
    const float* __restrict__ src, float* __restrict__ dst)
{
    int g = blockIdx.x;
    int b = g >> 7, p = g & 127;
    int tid = threadIdx.x;
    int w = tid >> 6, lane = tid & 63;
    int hh = lane >> 4;

    __shared__ __align__(16) float out_s[16][256];
    __shared__ float m_s[16][4], l_s[16][4];

    const float4* Kp4 = (const float4*)(Kp + (size_t)b * LLEN * HDIM);
    const float4* Vp4 = (const float4*)(Vp + (size_t)b * LLEN * HDIM);

    #pragma unroll
    for (int rr = 0; rr < 2; ++rr) {
        int q = rr ? (255 - p) : p;
        int bq = b * 256 + q;
        float4 qf = ((const float4*)(Q + (size_t)bq * HDIM))[lane];  // head = lane>>4
        bool tlq = tl[bq] != 0;
        int kmax = tlq ? (LLEN - 1) : q;   // causal skip: masked cols -> weight 0 exactly

        const float4* tmK4 = (const float4*)(tmK + (size_t)bq * LLEN * HDIM);
        const float4* tmV4 = (const float4*)(tmV + (size_t)bq * LLEN * HDIM);

        float4 acc = {0.f, 0.f, 0.f, 0.f};
        float m = -INFINITY, l = 0.f;

        for (int k = w; k <= kmax; k += 16) {
            int off = k * 64 + lane;
            float4 kv = Kp4[off];
            float4 tv = tmK4[off];
            float4 vv = Vp4[off];
            float4 tw = tmV4[off];
            float s = qf.x * (kv.x + tv.x) + qf.y * (kv.y + tv.y)
                    + qf.z * (kv.z + tv.z) + qf.w * (kv.w + tv.w);
            s += __shfl_xor(s, 1);
            s += __shfl_xor(s, 2);
            s += __shfl_xor(s, 4);
            s += __shfl_xor(s, 8);
            s = tlq ? NEGV : s * 0.125f;      // 1/sqrt(64); all-NEG row -> uniform
            float mn = fmaxf(m, s);
            float c = __expf(m - mn);          // m=-inf first iter -> c=0
            float e = __expf(s - mn);
            l = l * c + e;
            acc.x = fmaf(acc.x, c, e * (vv.x + tw.x));
            acc.y = fmaf(acc.y, c, e * (vv.y + tw.y));
            acc.z = fmaf(acc.z, c, e * (vv.z + tw.z));
            acc.w = fmaf(acc.w, c, e * (vv.w + tw.w));
            m = mn;
        }

        if ((lane & 15) == 0) { m_s[w][hh] = m; l_s[w][hh] = l; }
        *(float4*)&out_s[w][lane * 4] = acc;
        __syncthreads();

        if (tid < 256) {   // flash combine over 16 waves; head = col>>6
            int h = tid >> 6;
            float mt = -INFINITY;
            #pragma unroll
            for (int j = 0; j < 16; ++j) mt = fmaxf(mt, m_s[j][h]);
            float lt = 0.f, o = 0.f;
            #pragma unroll
            for (int j = 0; j < 16; ++j) {
                float f = __expf(m_s[j][h] - mt);   // inactive wave: exp(-inf)=0
                lt = fmaf(l_s[j][h], f, lt);
                o  = fmaf(out_s[j][tid], f, o);
            }
            size_t idx = (size_t)bq * HDIM + tid;
            dst[idx] = src[idx] + o / lt;
        }
        __syncthreads();   // out_s/m_s/l_s reused by next rr
    }
}

// ---- final RMSNorm --------------------------------------------------------
__global__ __launch_bounds__(256) void rmsnorm_kernel(
    const float* __restrict__ x, const float* __restrict__ w, float* __restrict__ y)
{
    int row = blockIdx.x;
    int tid = threadIdx.x;
    float v = x[(size_t)row * HDIM + tid];
    float ss = v * v;
    #pragma unroll
    for (int m = 1; m < 64; m <<= 1) ss += __shfl_xor(ss, m);
    __shared__ float red[4];
    if ((tid & 63) == 0) red[tid >> 6] = ss;
    __syncthreads();
    float tot = red[0] + red[1] + red[2] + red[3];
    float r = rsqrtf(tot * (1.0f / HDIM) + 1e-8f);
    y[(size_t)row * HDIM + tid] = v * r * w[tid];
}

extern "C" void kernel_launch(void* const* d_in, const int* in_sizes, int n_in,
                              void* d_out, int out_size, void* d_ws, size_t ws_size,
                              hipStream_t stream)
{
    const float* seqs = (const float*)d_in[0];
    const unsigned char* tl = (const unsigned char*)d_in[2];
    const float* tmK = (const float*)d_in[3];
    const float* tmV = (const float*)d_in[4];
    const float* apK = (const float*)d_in[5];
    const float* apV = (const float*)d_in[6];
    const float* ln_attn = (const float*)d_in[7];
    const float* Qw = (const float*)d_in[8];
    const float* Qb = (const float*)d_in[9];
    const float* Kw = (const float*)d_in[10];
    const float* Kb = (const float*)d_in[11];
    const float* Vw = (const float*)d_in[12];
    const float* Vb = (const float*)d_in[13];
    const float* ln_ffn = (const float*)d_in[14];
    const float* W1 = (const float*)d_in[15];
    const float* b1 = (const float*)d_in[16];
    const float* W2 = (const float*)d_in[17];
    const float* b2 = (const float*)d_in[18];
    const float* ln_last = (const float*)d_in[19];
    float* out = (float*)d_out;

    const size_t NROW = (size_t)MM * HDIM;
    float* s  = (float*)d_ws;
    float* qb = s  + NROW;
    float* kb = qb + NROW;
    float* vb = kb + NROW;
    float* tb = vb + NROW;

    for (int i = 0; i < 2; ++i) {
        const float* Qwi = Qw + (size_t)i * HDIM * HDIM;
        const float* Kwi = Kw + (size_t)i * HDIM * HDIM;
        const float* Vwi = Vw + (size_t)i * HDIM * HDIM;
        const float* W1i = W1 + (size_t)i * HDIM * HDIM;
        const float* W2i = W2 + (size_t)i * HDIM * HDIM;
        const float* cur = (i == 0) ? seqs : s;   // block0 reads seqs directly

        qkv_kernel<<<dim3(32, 12), 256, 0, stream>>>(
            cur, ln_attn + i * HDIM, Qwi, Qb + i * HDIM, Kwi, Kb + i * HDIM,
            Vwi, Vb + i * HDIM, apK, apV, qb, kb, vb);
        attn_kernel<<<512, 1024, 0, stream>>>(qb, kb, vb, tmK, tmV, tl, cur, s);
        gemm_kernel<<<dim3(32, 4), 256, 0, stream>>>(
            s, ln_ffn + i * HDIM, W1i, b1 + i * HDIM, nullptr, nullptr, tb, 1);
        gemm_kernel<<<dim3(32, 4), 256, 0, stream>>>(
            tb, nullptr, W2i, b2 + i * HDIM, s, tl, s, 0);
    }
    rmsnorm_kernel<<<MM, 256, 0, stream>>>(s, ln_last, out);
}